// Round 3
// baseline (286.888 us; speedup 1.0000x reference)
//
#include <hip/hip_runtime.h>

#define NC 91
#define NB 32
#define HW (1024 * 1024)

#define THREADS 256
#define PPT 64                          // pixels per thread
#define PIX_PER_BLOCK (THREADS * PPT)   // 16384
#define WPT 23                          // ceil(91/4) words, odd stride -> full bank spread

// Per-thread private histogram, 4 bins packed per 32-bit word (8-bit fields).
// Max increments per thread per bin = 2*PPT = 128 <= 255, so no field carry.
//
// KEY CHANGE vs round 2: the histogram is PRIVATE per thread, so atomicity is
// unnecessary. LDS atomics appear to serialize ~1 lane/cycle on the DS unit
// (110 us ~= 2 atomics/pixel at 64 lanes/cycle-each — matched rounds 0/1/2),
// while plain ds_read/ds_write are bank-parallel (~6 cyc/wave-instr). So use
// read + add + write. Same-word collision (x>>2 == t>>2, ~4.4%) is handled
// branchlessly: write t's word first, then x's word with the merged sum —
// last write wins with the correct total. Per-lane DS program order makes
// cross-pixel read-after-write safe.

__device__ __forceinline__ void proc_pixel(int x, int t, int* hp, int* s_inter) {
    const int wx = x >> 2, wt = t >> 2;
    const int ix = 1 << ((x & 3) << 3);
    const int it = 1 << ((t & 3) << 3);
    const int vx = hp[wx];
    const int vt = hp[wt];
    hp[wt] = vt + it;
    hp[wx] = vx + ix + (wx == wt ? it : 0);
    if (x == t) atomicAdd(&s_inter[x], 1);   // rare (~1/91), stays atomic
}

__global__ __launch_bounds__(256) void hist_kernel(const int* __restrict__ x,
                                                   const int* __restrict__ t,
                                                   int* __restrict__ g_hist,
                                                   int* __restrict__ g_inter) {
    __shared__ int s_hist[THREADS * WPT];   // 23,552 B packed private histograms
    __shared__ int s_inter[NC];             // block-wide intersection (rare hits)
    __shared__ int s_p[8][WPT * 4];         // stage-1 partials (8 chunks x 92 classes)

    const int tid = threadIdx.x;
    int* hp = &s_hist[tid * WPT];
#pragma unroll
    for (int j = 0; j < WPT; ++j) hp[j] = 0;
    if (tid < NC) s_inter[tid] = 0;
    __syncthreads();

    const int b = blockIdx.y;
    const long base = (long)b * HW + (long)blockIdx.x * PIX_PER_BLOCK;
    const int4* __restrict__ x4 = (const int4*)(x + base);
    const int4* __restrict__ t4 = (const int4*)(t + base);

#pragma unroll 4
    for (int i = 0; i < PPT / 4; ++i) {
        int4 xv = x4[i * THREADS + tid];
        int4 tv = t4[i * THREADS + tid];
        proc_pixel(xv.x, tv.x, hp, s_inter);
        proc_pixel(xv.y, tv.y, hp, s_inter);
        proc_pixel(xv.z, tv.z, hp, s_inter);
        proc_pixel(xv.w, tv.w, hp, s_inter);
    }
    __syncthreads();

    // Stage 1: reduce 256 private copies in 8 chunks of 32, unpacking 8-bit
    // fields into 32-bit partials (max 32*255 = 8160 per field, no overflow).
    // Lane w reads stride-WPT words: 32*WPT % 32 == 0 chunk offset -> 2-way
    // bank aliasing between the wave's 2 chunks, which is free.
    const int chunk = tid >> 5;
    const int w = tid & 31;
    if (w < WPT) {
        int f0 = 0, f1 = 0, f2 = 0, f3 = 0;
        const int kb = chunk * 32;
        for (int k = 0; k < 32; ++k) {
            unsigned v = (unsigned)s_hist[(kb + k) * WPT + w];
            f0 += (int)(v & 0xffu);
            f1 += (int)((v >> 8) & 0xffu);
            f2 += (int)((v >> 16) & 0xffu);
            f3 += (int)(v >> 24);
        }
        s_p[chunk][w * 4 + 0] = f0;
        s_p[chunk][w * 4 + 1] = f1;
        s_p[chunk][w * 4 + 2] = f2;
        s_p[chunk][w * 4 + 3] = f3;
    }
    __syncthreads();

    // Stage 2: combine 8 chunk partials, one global atomic per class.
    if (tid < NC) {
        int sum = 0;
#pragma unroll
        for (int ch = 0; ch < 8; ++ch) sum += s_p[ch][tid];
        if (sum) atomicAdd(&g_hist[b * NC + tid], sum);   // cnt_x + cnt_t
        const int in = s_inter[tid];
        if (in)  atomicAdd(&g_inter[b * NC + tid], in);
    }
}

__global__ __launch_bounds__(64) void finalize_kernel(const int* __restrict__ g_hist,
                                                      const int* __restrict__ g_inter,
                                                      const float* __restrict__ smooth,
                                                      float* __restrict__ out) {
    const int b = blockIdx.x;
    const int lane = threadIdx.x;  // 0..63
    const float s = smooth[0];
    float acc = 0.0f;
    for (int c = lane; c < NC; c += 64) {
        float in = (float)g_inter[b * NC + c];
        float ht = (float)g_hist[b * NC + c];   // cnt_x + cnt_t
        // union = cnt_x + cnt_t - inter
        acc += (in + s) / (ht - in + s);
    }
#pragma unroll
    for (int off = 32; off > 0; off >>= 1)
        acc += __shfl_down(acc, off, 64);
    if (lane == 0) out[b] = acc / (float)NC;
}

extern "C" void kernel_launch(void* const* d_in, const int* in_sizes, int n_in,
                              void* d_out, int out_size, void* d_ws, size_t ws_size,
                              hipStream_t stream) {
    const int* x = (const int*)d_in[0];
    const int* t = (const int*)d_in[1];
    const float* smooth = (const float*)d_in[2];
    float* out = (float*)d_out;

    int* g_hist = (int*)d_ws;
    int* g_inter = g_hist + NB * NC;

    hipMemsetAsync(d_ws, 0, 2 * NB * NC * sizeof(int), stream);

    dim3 grid(HW / PIX_PER_BLOCK, NB);  // 64 x 32 = 2048 blocks
    hist_kernel<<<grid, THREADS, 0, stream>>>(x, t, g_hist, g_inter);
    finalize_kernel<<<NB, 64, 0, stream>>>(g_hist, g_inter, smooth, out);
}

// Round 4
// 281.892 us; speedup vs baseline: 1.0177x; 1.0177x over previous
//
#include <hip/hip_runtime.h>

#define NC 91
#define NB 32
#define HW (1024 * 1024)

#define THREADS 256
#define PPT 64                          // pixels per thread
#define PIX_PER_BLOCK (THREADS * PPT)   // 16384
#define NCOPY 8                         // histogram sub-copies (copy = lane&7)

// Round-4 structure: per-BLOCK 8-copy 32-bit histogram, fire-and-forget
// LDS atomics (no return value -> no lgkmcnt waits in the loop).
//  - LDS 3.3 KB/block -> 8 blocks/CU -> 100% wave occupancy (was 48%).
//  - copy = lane&7: same-address collisions within a wave-op ~2-way (free).
//  - copy stride 91 words: copy base offsets k*91 mod 32 all distinct banks.
//  - x==t folds into a single +2 update, so ~1.96 DS updates/pixel + rare
//    intersection atomic (exec-mask empty ~49% of wave-ops -> execz skip).
//  - depth-2 explicit prefetch keeps >=4 global loads in flight per wave.

__device__ __forceinline__ void proc_pixel(int x, int t, int* hp, int* s_inter) {
    atomicAdd(&hp[x], x == t ? 2 : 1);   // cnt_x + cnt_t contribution
    if (x != t) atomicAdd(&hp[t], 1);
    else        atomicAdd(&s_inter[x], 1);
}

__global__ __launch_bounds__(256, 8) void hist_kernel(const int* __restrict__ x,
                                                      const int* __restrict__ t,
                                                      int* __restrict__ g_hist,
                                                      int* __restrict__ g_inter) {
    __shared__ int s_h[NCOPY * NC];   // 728 words = 2912 B
    __shared__ int s_inter[NC];

    const int tid = threadIdx.x;
    for (int j = tid; j < NCOPY * NC; j += THREADS) s_h[j] = 0;
    if (tid < NC) s_inter[tid] = 0;
    __syncthreads();

    int* hp = &s_h[(tid & 7) * NC];

    const int b = blockIdx.y;
    const long base = (long)b * HW + (long)blockIdx.x * PIX_PER_BLOCK;
    const int4* __restrict__ x4 = (const int4*)(x + base);
    const int4* __restrict__ t4 = (const int4*)(t + base);

    const int n = PPT / 4;   // 16 iterations, 4 pixels each
    int4 xv0 = x4[tid],           tv0 = t4[tid];
    int4 xv1 = x4[THREADS + tid], tv1 = t4[THREADS + tid];

    for (int i = 0; i < n; ++i) {
        const int pf = (i + 2 < n) ? (i + 2) : (n - 1);   // clamped prefetch
        int4 xn = x4[pf * THREADS + tid];
        int4 tn = t4[pf * THREADS + tid];

        proc_pixel(xv0.x, tv0.x, hp, s_inter);
        proc_pixel(xv0.y, tv0.y, hp, s_inter);
        proc_pixel(xv0.z, tv0.z, hp, s_inter);
        proc_pixel(xv0.w, tv0.w, hp, s_inter);

        xv0 = xv1; tv0 = tv1;
        xv1 = xn;  tv1 = tn;
    }
    __syncthreads();

    // Epilogue: fold 8 copies, one global atomic per class.
    if (tid < NC) {
        int sum = 0;
#pragma unroll
        for (int k = 0; k < NCOPY; ++k) sum += s_h[k * NC + tid];
        if (sum) atomicAdd(&g_hist[b * NC + tid], sum);   // cnt_x + cnt_t
        const int in = s_inter[tid];
        if (in)  atomicAdd(&g_inter[b * NC + tid], in);
    }
}

__global__ __launch_bounds__(64) void finalize_kernel(const int* __restrict__ g_hist,
                                                      const int* __restrict__ g_inter,
                                                      const float* __restrict__ smooth,
                                                      float* __restrict__ out) {
    const int b = blockIdx.x;
    const int lane = threadIdx.x;  // 0..63
    const float s = smooth[0];
    float acc = 0.0f;
    for (int c = lane; c < NC; c += 64) {
        float in = (float)g_inter[b * NC + c];
        float ht = (float)g_hist[b * NC + c];   // cnt_x + cnt_t
        // union = cnt_x + cnt_t - inter
        acc += (in + s) / (ht - in + s);
    }
#pragma unroll
    for (int off = 32; off > 0; off >>= 1)
        acc += __shfl_down(acc, off, 64);
    if (lane == 0) out[b] = acc / (float)NC;
}

extern "C" void kernel_launch(void* const* d_in, const int* in_sizes, int n_in,
                              void* d_out, int out_size, void* d_ws, size_t ws_size,
                              hipStream_t stream) {
    const int* x = (const int*)d_in[0];
    const int* t = (const int*)d_in[1];
    const float* smooth = (const float*)d_in[2];
    float* out = (float*)d_out;

    int* g_hist = (int*)d_ws;
    int* g_inter = g_hist + NB * NC;

    hipMemsetAsync(d_ws, 0, 2 * NB * NC * sizeof(int), stream);

    dim3 grid(HW / PIX_PER_BLOCK, NB);  // 64 x 32 = 2048 blocks (8/CU, 1 full round)
    hist_kernel<<<grid, THREADS, 0, stream>>>(x, t, g_hist, g_inter);
    finalize_kernel<<<NB, 64, 0, stream>>>(g_hist, g_inter, smooth, out);
}